// Round 5
// baseline (551.240 us; speedup 1.0000x reference)
//
#include <hip/hip_runtime.h>
#include <hip/hip_bf16.h>
#include <hip/hip_fp16.h>

#define IN_CH   256
#define NOUT    128      // HEADS*OUT_CH
#define OUT_CH  64
#define NEG     0.2f

typedef __attribute__((ext_vector_type(8))) short bf16x8;   // 8 bf16 = 4 VGPRs
typedef __attribute__((ext_vector_type(4))) float f32x4;

static __device__ __forceinline__ short f2bf(float f) {
    __hip_bfloat16 h = __float2bfloat16(f);
    return *reinterpret_cast<short*>(&h);
}

// ---------- Wt[n][k] = bf16(W[k][n])  (W: 256x128 f32) ----------
__global__ void k_transpose_w(const float* __restrict__ W,
                              __hip_bfloat16* __restrict__ Wt) {
    int i = blockIdx.x * blockDim.x + threadIdx.x;
    if (i < IN_CH * NOUT) {
        int n = i >> 8, k = i & 255;
        Wt[i] = __float2bfloat16(W[k * NOUT + n]);
    }
}

// ---------- x = bf16(z) @ bf16(W) + fused attention scores ----------
// one wave = 16 rows x 128 cols, mfma_f32_16x16x32_bf16
// A: lane holds A[m=lane&15][k=quad*8+j];  B: lane holds B[k=quad*8+j][n=lane&15]
// C/D: col=lane&15, row=quad*4+reg
__global__ __launch_bounds__(256) void k_gemm_x(
        const float* __restrict__ z,
        const __hip_bfloat16* __restrict__ wt,
        const float* __restrict__ att_s,
        const float* __restrict__ att_d,
        __hip_bfloat16* __restrict__ x,
        float* __restrict__ a_src, float* __restrict__ a_dst, int nTiles) {
    int wid  = (blockIdx.x * blockDim.x + threadIdx.x) >> 6;
    if (wid >= nTiles) return;
    int lane = threadIdx.x & 63;
    int m = lane & 15, quad = lane >> 4;
    int rbase = wid * 16;
    const float* zp = z + (size_t)(rbase + m) * IN_CH + quad * 8;
    const short* wp = (const short*)wt + m * IN_CH + quad * 8;
    f32x4 acc[8] = {};
#pragma unroll
    for (int kb = 0; kb < 8; ++kb) {
        float4 f0 = *(const float4*)(zp + kb * 32);
        float4 f1 = *(const float4*)(zp + kb * 32 + 4);
        bf16x8 a;
        a[0] = f2bf(f0.x); a[1] = f2bf(f0.y); a[2] = f2bf(f0.z); a[3] = f2bf(f0.w);
        a[4] = f2bf(f1.x); a[5] = f2bf(f1.y); a[6] = f2bf(f1.z); a[7] = f2bf(f1.w);
#pragma unroll
        for (int n = 0; n < 8; ++n) {
            bf16x8 b = *(const bf16x8*)(wp + n * 16 * IN_CH + kb * 32);
            acc[n] = __builtin_amdgcn_mfma_f32_16x16x32_bf16(a, b, acc[n], 0, 0, 0);
        }
    }
    // store x (bf16)
#pragma unroll
    for (int n = 0; n < 8; ++n)
#pragma unroll
        for (int r = 0; r < 4; ++r) {
            int row = rbase + quad * 4 + r;
            x[(size_t)row * NOUT + n * 16 + m] = __float2bfloat16(acc[n][r]);
        }
    // fused attention scores
    float asv[8], adv[8];
#pragma unroll
    for (int n = 0; n < 8; ++n) {
        asv[n] = att_s[n * 16 + m];
        adv[n] = att_d[n * 16 + m];
    }
    float ps0[4] = {}, ps1[4] = {}, pd0[4] = {}, pd1[4] = {};
#pragma unroll
    for (int r = 0; r < 4; ++r)
#pragma unroll
        for (int n = 0; n < 4; ++n) {
            ps0[r] += acc[n][r] * asv[n];
            ps1[r] += acc[n + 4][r] * asv[n + 4];
            pd0[r] += acc[n][r] * adv[n];
            pd1[r] += acc[n + 4][r] * adv[n + 4];
        }
#pragma unroll
    for (int msk = 1; msk < 16; msk <<= 1)
#pragma unroll
        for (int r = 0; r < 4; ++r) {
            ps0[r] += __shfl_xor(ps0[r], msk);
            ps1[r] += __shfl_xor(ps1[r], msk);
            pd0[r] += __shfl_xor(pd0[r], msk);
            pd1[r] += __shfl_xor(pd1[r], msk);
        }
    if (m < 4) {
        int r = m;
        int row = rbase + quad * 4 + r;
        ((float2*)a_src)[row] = make_float2(ps0[r], ps1[r]);
        ((float2*)a_dst)[row] = make_float2(pd0[r], pd1[r]);
    }
}

// ---------- build: fixed-capacity buckets, one pass over edges ----------
// bucket d: slot 0 = self-loop, slots 1..deg[d] = real edges (order arbitrary)
// epk[slot] = { half2(e0,e1) bits, src }
__global__ void k_build(const int* __restrict__ ei,
                        const float* __restrict__ a_src, const float* __restrict__ a_dst,
                        int* __restrict__ deg, int2* __restrict__ epk,
                        int E, int N, int cap) {
    int e = blockIdx.x * blockDim.x + threadIdx.x;
    if (e < E) {
        int s = ei[e], d = ei[E + e];
        float2 as = ((const float2*)a_src)[s];
        float2 ad = ((const float2*)a_dst)[d];
        float l0 = as.x + ad.x; l0 = (l0 > 0.f) ? l0 : NEG * l0;
        float l1 = as.y + ad.y; l1 = (l1 > 0.f) ? l1 : NEG * l1;
        __half2 h2;
        h2.x = __float2half(__expf(l0));
        h2.y = __float2half(__expf(l1));
        int pos = atomicAdd(&deg[d], 1);
        if (pos < cap - 1)   // impossible overflow guard (Poisson(32), cap>=72)
            epk[(size_t)d * cap + 1 + pos] = make_int2(*reinterpret_cast<int*>(&h2), s);
    } else if (e < E + N) {
        int v = e - E;   // self-loop (coalesced loads, slot 0)
        float2 as = ((const float2*)a_src)[v];
        float2 ad = ((const float2*)a_dst)[v];
        float l0 = as.x + ad.x; l0 = (l0 > 0.f) ? l0 : NEG * l0;
        float l1 = as.y + ad.y; l1 = (l1 > 0.f) ? l1 : NEG * l1;
        __half2 h2;
        h2.x = __float2half(__expf(l0));
        h2.y = __float2half(__expf(l1));
        epk[(size_t)v * cap] = make_int2(*reinterpret_cast<int*>(&h2), v);
    }
}

// ---------- main GAT aggregation: one wave per dst node, single fused pass ----------
// out_h = (sum_i e_i x_i) / (sum_i e_i)
__global__ __launch_bounds__(256) void k_gat_agg(
        const int2* __restrict__ epk, const int* __restrict__ deg,
        const __hip_bfloat16* __restrict__ x, const float* __restrict__ bias,
        float* __restrict__ out, int N, int cap) {
    int wid  = (blockIdx.x * blockDim.x + threadIdx.x) >> 6;
    if (wid >= N) return;
    int lane = threadIdx.x & 63;
    int d = deg[wid];
    if (d > cap - 1) d = cap - 1;
    int beg = wid * cap, end = beg + 1 + d;
    int h = lane >> 5;   // lanes 0..31: head0 chans, 32..63: head1 chans
    const __hip_bfloat162* xv = (const __hip_bfloat162*)x;

    float ax[4] = {}, ay[4] = {}, dn[4] = {};   // 4 independent chains
    int i = beg;
    for (; i + 3 < end; i += 4) {
#pragma unroll
        for (int u = 0; u < 4; ++u) {
            int2 p = epk[i + u];
            __half2 h2 = *reinterpret_cast<__half2*>(&p.x);
            float2 ef = __half22float2(h2);
            float e = h ? ef.y : ef.x;
            __hip_bfloat162 f = xv[(size_t)p.y * 64 + lane];
            ax[u] += e * __bfloat162float(f.x);
            ay[u] += e * __bfloat162float(f.y);
            dn[u] += e;
        }
    }
    for (; i < end; ++i) {
        int2 p = epk[i];
        __half2 h2 = *reinterpret_cast<__half2*>(&p.x);
        float2 ef = __half22float2(h2);
        float e = h ? ef.y : ef.x;
        __hip_bfloat162 f = xv[(size_t)p.y * 64 + lane];
        ax[0] += e * __bfloat162float(f.x);
        ay[0] += e * __bfloat162float(f.y);
        dn[0] += e;
    }
    float inv = 1.f / ((dn[0] + dn[1]) + (dn[2] + dn[3]));
    float accx = ((ax[0] + ax[1]) + (ax[2] + ax[3])) * inv;
    float accy = ((ay[0] + ay[1]) + (ay[2] + ay[3])) * inv;
    // mean over heads: lane L<32 has head0 chans {2L,2L+1}; lane L+32 has head1 same chans
    float o0 = accx + __shfl_xor(accx, 32);
    float o1 = accy + __shfl_xor(accy, 32);
    if (lane < 32) {
        int c = 2 * lane;
        float2 o;
        o.x = 0.5f * o0 + bias[c];
        o.y = 0.5f * o1 + bias[c + 1];
        ((float2*)out)[(size_t)wid * 32 + lane] = o;
    }
}

extern "C" void kernel_launch(void* const* d_in, const int* in_sizes, int n_in,
                              void* d_out, int out_size, void* d_ws, size_t ws_size,
                              hipStream_t stream) {
    const float* z     = (const float*)d_in[0];
    const int*   ei    = (const int*)d_in[1];
    const float* W     = (const float*)d_in[2];
    const float* att_s = (const float*)d_in[3];
    const float* att_d = (const float*)d_in[4];
    const float* bias  = (const float*)d_in[5];
    float* out = (float*)d_out;

    const int N = in_sizes[0] / IN_CH;     // 100000
    const int E = in_sizes[1] / 2;         // 3200000
    const int Etot = E + N;

    // workspace carve-up (256B aligned)
    size_t off = 0;
    auto alloc = [&](size_t bytes) {
        void* p = (char*)d_ws + off;
        off += (bytes + 255) & ~(size_t)255;
        return p;
    };
    __hip_bfloat16* x    = (__hip_bfloat16*)alloc((size_t)N * NOUT * 2);
    __hip_bfloat16* Wt   = (__hip_bfloat16*)alloc((size_t)IN_CH * NOUT * 2);
    float* a_src         = (float*)alloc((size_t)N * 2 * 4);
    float* a_dst         = (float*)alloc((size_t)N * 2 * 4);
    int*   deg           = (int*)alloc((size_t)N * 4);
    // bucket capacity from remaining workspace (prefer 96; >=72 is tail-safe)
    size_t avail = (ws_size > off + 4096) ? (ws_size - off - 4096) : 0;
    int cap = (int)(avail / ((size_t)N * 8));
    if (cap > 96) cap = 96;
    int2*  epk           = (int2*)alloc((size_t)N * cap * 8);
    (void)Etot;

    const int nTiles = N / 16;                 // 6250

    hipMemsetAsync(deg, 0, (size_t)N * 4, stream);
    k_transpose_w<<<(IN_CH * NOUT + 255) / 256, 256, 0, stream>>>(W, Wt);
    k_gemm_x<<<(nTiles + 3) / 4, 256, 0, stream>>>(z, Wt, att_s, att_d, x, a_src, a_dst, nTiles);
    k_build<<<(E + N + 255) / 256, 256, 0, stream>>>(ei, a_src, a_dst, deg, epk, E, N, cap);
    k_gat_agg<<<(N + 3) / 4, 256, 0, stream>>>(epk, deg, x, bias, out, N, cap);
}

// Round 6
// 442.673 us; speedup vs baseline: 1.2453x; 1.2453x over previous
//
#include <hip/hip_runtime.h>
#include <hip/hip_bf16.h>
#include <hip/hip_fp16.h>

#define IN_CH   256
#define NOUT    128      // HEADS*OUT_CH
#define OUT_CH  64
#define NEG     0.2f

#define NBINS     256
#define BIN_SHIFT 9
#define NPB       512       // nodes per bin
#define CAPB      18432     // per-bin edge capacity (mean ~16.3k, +16 sigma)
#define EPT       8         // edges per thread in pass1

typedef __attribute__((ext_vector_type(8))) short bf16x8;   // 8 bf16 = 4 VGPRs
typedef __attribute__((ext_vector_type(4))) float f32x4;

static __device__ __forceinline__ short f2bf(float f) {
    __hip_bfloat16 h = __float2bfloat16(f);
    return *reinterpret_cast<short*>(&h);
}

static __device__ __forceinline__ int pack_e(float l0, float l1) {
    __half2 h2;
    h2.x = __float2half(__expf(l0));
    h2.y = __float2half(__expf(l1));
    return *reinterpret_cast<int*>(&h2);
}

// ---------- Wt[n][k] = bf16(W[k][n])  (W: 256x128 f32) ----------
__global__ void k_transpose_w(const float* __restrict__ W,
                              __hip_bfloat16* __restrict__ Wt) {
    int i = blockIdx.x * blockDim.x + threadIdx.x;
    if (i < IN_CH * NOUT) {
        int n = i >> 8, k = i & 255;
        Wt[i] = __float2bfloat16(W[k * NOUT + n]);
    }
}

// ---------- x = bf16(z) @ bf16(W) + fused attention scores ----------
__global__ __launch_bounds__(256) void k_gemm_x(
        const float* __restrict__ z,
        const __hip_bfloat16* __restrict__ wt,
        const float* __restrict__ att_s,
        const float* __restrict__ att_d,
        __hip_bfloat16* __restrict__ x,
        float* __restrict__ a_src, float* __restrict__ a_dst, int nTiles) {
    int wid  = (blockIdx.x * blockDim.x + threadIdx.x) >> 6;
    if (wid >= nTiles) return;
    int lane = threadIdx.x & 63;
    int m = lane & 15, quad = lane >> 4;
    int rbase = wid * 16;
    const float* zp = z + (size_t)(rbase + m) * IN_CH + quad * 8;
    const short* wp = (const short*)wt + m * IN_CH + quad * 8;
    f32x4 acc[8] = {};
#pragma unroll
    for (int kb = 0; kb < 8; ++kb) {
        float4 f0 = *(const float4*)(zp + kb * 32);
        float4 f1 = *(const float4*)(zp + kb * 32 + 4);
        bf16x8 a;
        a[0] = f2bf(f0.x); a[1] = f2bf(f0.y); a[2] = f2bf(f0.z); a[3] = f2bf(f0.w);
        a[4] = f2bf(f1.x); a[5] = f2bf(f1.y); a[6] = f2bf(f1.z); a[7] = f2bf(f1.w);
#pragma unroll
        for (int n = 0; n < 8; ++n) {
            bf16x8 b = *(const bf16x8*)(wp + n * 16 * IN_CH + kb * 32);
            acc[n] = __builtin_amdgcn_mfma_f32_16x16x32_bf16(a, b, acc[n], 0, 0, 0);
        }
    }
#pragma unroll
    for (int n = 0; n < 8; ++n)
#pragma unroll
        for (int r = 0; r < 4; ++r) {
            int row = rbase + quad * 4 + r;
            x[(size_t)row * NOUT + n * 16 + m] = __float2bfloat16(acc[n][r]);
        }
    // fused attention scores (reduced over the 16 m-lanes of each quad)
    float asv[8], adv[8];
#pragma unroll
    for (int n = 0; n < 8; ++n) {
        asv[n] = att_s[n * 16 + m];
        adv[n] = att_d[n * 16 + m];
    }
    float ps0[4] = {}, ps1[4] = {}, pd0[4] = {}, pd1[4] = {};
#pragma unroll
    for (int r = 0; r < 4; ++r)
#pragma unroll
        for (int n = 0; n < 4; ++n) {
            ps0[r] += acc[n][r] * asv[n];
            ps1[r] += acc[n + 4][r] * asv[n + 4];
            pd0[r] += acc[n][r] * adv[n];
            pd1[r] += acc[n + 4][r] * adv[n + 4];
        }
#pragma unroll
    for (int msk = 1; msk < 16; msk <<= 1)
#pragma unroll
        for (int r = 0; r < 4; ++r) {
            ps0[r] += __shfl_xor(ps0[r], msk);
            ps1[r] += __shfl_xor(ps1[r], msk);
            pd0[r] += __shfl_xor(pd0[r], msk);
            pd1[r] += __shfl_xor(pd1[r], msk);
        }
    if (m < 4) {
        int r = m;
        int row = rbase + quad * 4 + r;
        ((float2*)a_src)[row] = make_float2(ps0[r], ps1[r]);
        ((float2*)a_dst)[row] = make_float2(pd0[r], pd1[r]);
    }
}

// ---------- pass1: route edges into 512-node bins with block-chunked writes ----------
// binned[bin*CAPB + slot] = { half2(e0,e1) bits, (dstLow<<17)|src }
__global__ __launch_bounds__(256) void k_pass1(
        const int* __restrict__ ei,
        const float* __restrict__ a_src, const float* __restrict__ a_dst,
        int* __restrict__ gcnt, int2* __restrict__ binned, int E) {
    __shared__ int lcnt[NBINS];
    __shared__ int lptr[NBINS];
    int t = threadIdx.x;
    int base = blockIdx.x * (256 * EPT);
    if (t < NBINS) lcnt[t] = 0;
    __syncthreads();

    int2 pay[EPT];
    int  bn[EPT];
#pragma unroll
    for (int j = 0; j < EPT; ++j) {
        int e = base + j * 256 + t;
        bn[j] = -1;
        if (e < E) {
            int s = ei[e], d = ei[E + e];
            float2 as = ((const float2*)a_src)[s];
            float2 ad = ((const float2*)a_dst)[d];
            float l0 = as.x + ad.x; l0 = (l0 > 0.f) ? l0 : NEG * l0;
            float l1 = as.y + ad.y; l1 = (l1 > 0.f) ? l1 : NEG * l1;
            pay[j] = make_int2(pack_e(l0, l1), ((d & (NPB - 1)) << 17) | s);
            bn[j] = d >> BIN_SHIFT;
            atomicAdd(&lcnt[bn[j]], 1);
        }
    }
    __syncthreads();
    if (t < NBINS) {
        int c = lcnt[t];
        lptr[t] = (c > 0) ? atomicAdd(&gcnt[t], c) : 0;
    }
    __syncthreads();
#pragma unroll
    for (int j = 0; j < EPT; ++j) {
        if (bn[j] >= 0) {
            int pos = atomicAdd(&lptr[bn[j]], 1);
            if (pos < CAPB)
                binned[(size_t)bn[j] * CAPB + pos] = pay[j];
        }
    }
}

// ---------- bin-level exclusive scan: binBase[b] = sum_{b'<b} (edges+nodes) ----------
__global__ void k_binscan(const int* __restrict__ gcnt, int* __restrict__ binBase,
                          int* __restrict__ offs, int N) {
    __shared__ int sd[NBINS];
    int t = threadIdx.x;
    int nodes = N - t * NPB;
    nodes = (nodes < 0) ? 0 : ((nodes > NPB) ? NPB : nodes);
    int c = gcnt[t];
    if (c > CAPB) c = CAPB;
    int v = c + nodes;
    sd[t] = v;
    __syncthreads();
    for (int off = 1; off < NBINS; off <<= 1) {
        int u = (t >= off) ? sd[t - off] : 0;
        __syncthreads();
        sd[t] += u;
        __syncthreads();
    }
    binBase[t] = sd[t] - v;   // exclusive
    if (t == NBINS - 1) offs[N] = sd[t];
}

// ---------- pass2: per-bin LDS counting sort -> dense CSR epk + offs ----------
// dst d's region: [offs[d], offs[d+1]); slot offs[d] = self-loop.
__global__ __launch_bounds__(1024) void k_pass2(
        const int2* __restrict__ binned, const int* __restrict__ gcnt,
        const int* __restrict__ binBase,
        const float* __restrict__ a_src, const float* __restrict__ a_dst,
        int2* __restrict__ epk, int* __restrict__ offs, int N) {
    __shared__ int lh[NPB];   // hist, then write-ptr
    __shared__ int lx[NPB];   // inclusive scan
    int b = blockIdx.x, t = threadIdx.x;
    int nodes = N - b * NPB;
    nodes = (nodes < 0) ? 0 : ((nodes > NPB) ? NPB : nodes);
    if (nodes == 0) return;
    int cnt = gcnt[b];
    if (cnt > CAPB) cnt = CAPB;
    int base = binBase[b];
    const int2* src = binned + (size_t)b * CAPB;

    if (t < NPB) lh[t] = (t < nodes) ? 1 : 0;   // self-loop slot
    __syncthreads();
    for (int i = t; i < cnt; i += 1024)
        atomicAdd(&lh[(src[i].y >> 17) & (NPB - 1)], 1);
    __syncthreads();
    // inclusive scan of lh into lx
    if (t < NPB) lx[t] = lh[t];
    __syncthreads();
    for (int off = 1; off < NPB; off <<= 1) {
        int u = (t < NPB && t >= off) ? lx[t - off] : 0;
        __syncthreads();
        if (t < NPB) lx[t] += u;
        __syncthreads();
    }
    int excl = 0;
    if (t < NPB) {
        excl = lx[t] - lh[t];
        lh[t] = excl + 1;     // edge write-ptr starts after self slot
    }
    __syncthreads();
    // self-loops + offs
    if (t < nodes) {
        int d = b * NPB + t;
        float2 as = ((const float2*)a_src)[d];
        float2 ad = ((const float2*)a_dst)[d];
        float l0 = as.x + ad.x; l0 = (l0 > 0.f) ? l0 : NEG * l0;
        float l1 = as.y + ad.y; l1 = (l1 > 0.f) ? l1 : NEG * l1;
        epk[base + excl] = make_int2(pack_e(l0, l1), d);
        offs[d] = base + excl;
    }
    // placement (scattered 8B stores within a ~134KB window -> L2-merged)
    for (int i = t; i < cnt; i += 1024) {
        int2 p = src[i];
        int dLow = (p.y >> 17) & (NPB - 1);
        int pos = atomicAdd(&lh[dLow], 1);
        epk[base + pos] = make_int2(p.x, p.y & 0x1FFFF);
    }
}

// ---------- main GAT aggregation: one wave per dst node, single fused pass ----------
// out_h = (sum_i e_i x_i) / (sum_i e_i)
__global__ __launch_bounds__(256) void k_gat_agg(
        const int2* __restrict__ epk, const int* __restrict__ offs,
        const __hip_bfloat16* __restrict__ x, const float* __restrict__ bias,
        float* __restrict__ out, int N) {
    int wid  = (blockIdx.x * blockDim.x + threadIdx.x) >> 6;
    if (wid >= N) return;
    int lane = threadIdx.x & 63;
    int beg = offs[wid], end = offs[wid + 1];
    int h = lane >> 5;   // lanes 0..31: head0 chans, 32..63: head1 chans
    const __hip_bfloat162* xv = (const __hip_bfloat162*)x;

    float ax[4] = {}, ay[4] = {}, dn[4] = {};   // 4 independent chains
    int i = beg;
    for (; i + 3 < end; i += 4) {
#pragma unroll
        for (int u = 0; u < 4; ++u) {
            int2 p = epk[i + u];
            __half2 h2 = *reinterpret_cast<__half2*>(&p.x);
            float2 ef = __half22float2(h2);
            float e = h ? ef.y : ef.x;
            __hip_bfloat162 f = xv[(size_t)p.y * 64 + lane];
            ax[u] += e * __bfloat162float(f.x);
            ay[u] += e * __bfloat162float(f.y);
            dn[u] += e;
        }
    }
    for (; i < end; ++i) {
        int2 p = epk[i];
        __half2 h2 = *reinterpret_cast<__half2*>(&p.x);
        float2 ef = __half22float2(h2);
        float e = h ? ef.y : ef.x;
        __hip_bfloat162 f = xv[(size_t)p.y * 64 + lane];
        ax[0] += e * __bfloat162float(f.x);
        ay[0] += e * __bfloat162float(f.y);
        dn[0] += e;
    }
    float inv = 1.f / ((dn[0] + dn[1]) + (dn[2] + dn[3]));
    float accx = ((ax[0] + ax[1]) + (ax[2] + ax[3])) * inv;
    float accy = ((ay[0] + ay[1]) + (ay[2] + ay[3])) * inv;
    float o0 = accx + __shfl_xor(accx, 32);
    float o1 = accy + __shfl_xor(accy, 32);
    if (lane < 32) {
        int c = 2 * lane;
        float2 o;
        o.x = 0.5f * o0 + bias[c];
        o.y = 0.5f * o1 + bias[c + 1];
        ((float2*)out)[(size_t)wid * 32 + lane] = o;
    }
}

extern "C" void kernel_launch(void* const* d_in, const int* in_sizes, int n_in,
                              void* d_out, int out_size, void* d_ws, size_t ws_size,
                              hipStream_t stream) {
    const float* z     = (const float*)d_in[0];
    const int*   ei    = (const int*)d_in[1];
    const float* W     = (const float*)d_in[2];
    const float* att_s = (const float*)d_in[3];
    const float* att_d = (const float*)d_in[4];
    const float* bias  = (const float*)d_in[5];
    float* out = (float*)d_out;

    const int N = in_sizes[0] / IN_CH;     // 100000
    const int E = in_sizes[1] / 2;         // 3200000
    const int Etot = E + N;

    // workspace carve-up (256B aligned)
    size_t off = 0;
    auto alloc = [&](size_t bytes) {
        void* p = (char*)d_ws + off;
        off += (bytes + 255) & ~(size_t)255;
        return p;
    };
    __hip_bfloat16* x    = (__hip_bfloat16*)alloc((size_t)N * NOUT * 2);
    __hip_bfloat16* Wt   = (__hip_bfloat16*)alloc((size_t)IN_CH * NOUT * 2);
    float* a_src         = (float*)alloc((size_t)N * 2 * 4);
    float* a_dst         = (float*)alloc((size_t)N * 2 * 4);
    int*   gcnt          = (int*)alloc(NBINS * 4);
    int*   binBase       = (int*)alloc(NBINS * 4);
    int*   offs          = (int*)alloc((size_t)(N + 1) * 4);
    int2*  binned        = (int2*)alloc((size_t)NBINS * CAPB * 8);
    int2*  epk           = (int2*)alloc((size_t)Etot * 8);
    (void)ws_size;

    const int nTiles = N / 16;                 // 6250
    const int p1Blocks = (E + 256 * EPT - 1) / (256 * EPT);

    hipMemsetAsync(gcnt, 0, NBINS * 4, stream);
    k_transpose_w<<<(IN_CH * NOUT + 255) / 256, 256, 0, stream>>>(W, Wt);
    k_gemm_x<<<(nTiles + 3) / 4, 256, 0, stream>>>(z, Wt, att_s, att_d, x, a_src, a_dst, nTiles);
    k_pass1<<<p1Blocks, 256, 0, stream>>>(ei, a_src, a_dst, gcnt, binned, E);
    k_binscan<<<1, NBINS, 0, stream>>>(gcnt, binBase, offs, N);
    k_pass2<<<NBINS, 1024, 0, stream>>>(binned, gcnt, binBase, a_src, a_dst, epk, offs, N);
    k_gat_agg<<<(N + 3) / 4, 256, 0, stream>>>(epk, offs, x, bias, out, N);
}

// Round 8
// 428.873 us; speedup vs baseline: 1.2853x; 1.0322x over previous
//
#include <hip/hip_runtime.h>
#include <hip/hip_bf16.h>
#include <hip/hip_fp16.h>

#define IN_CH   256
#define NOUT    128      // HEADS*OUT_CH
#define OUT_CH  64
#define NEG     0.2f

#define NBINS     256
#define BIN_SHIFT 9
#define NPB       512       // nodes per bin
// Only ceil(100000/512)=196 bins are populated -> per-bin mean = E*512/N = 16384.
// CAPB = 18432 = mean + 16 sigma (sigma ~128). (R7 bug: 14336 < mean dropped edges!)
#define CAPB      18432
#define EPT       16        // edges per thread in pass1

typedef __attribute__((ext_vector_type(8))) short bf16x8;   // 8 bf16 = 4 VGPRs
typedef __attribute__((ext_vector_type(4))) float f32x4;

static __device__ __forceinline__ short f2bf(float f) {
    __hip_bfloat16 h = __float2bfloat16(f);
    return *reinterpret_cast<short*>(&h);
}

static __device__ __forceinline__ int pack_e(float l0, float l1) {
    __half2 h2;
    h2.x = __float2half(__expf(l0));
    h2.y = __float2half(__expf(l1));
    return *reinterpret_cast<int*>(&h2);
}

// ---------- Wt[n][k] = bf16(W[k][n])  (W: 256x128 f32) ----------
__global__ void k_transpose_w(const float* __restrict__ W,
                              __hip_bfloat16* __restrict__ Wt) {
    int i = blockIdx.x * blockDim.x + threadIdx.x;
    if (i < IN_CH * NOUT) {
        int n = i >> 8, k = i & 255;
        Wt[i] = __float2bfloat16(W[k * NOUT + n]);
    }
}

// ---------- x = bf16(z) @ bf16(W) + fused attention scores ----------
__global__ __launch_bounds__(256) void k_gemm_x(
        const float* __restrict__ z,
        const __hip_bfloat16* __restrict__ wt,
        const float* __restrict__ att_s,
        const float* __restrict__ att_d,
        __hip_bfloat16* __restrict__ x,
        float* __restrict__ a_src, float* __restrict__ a_dst, int nTiles) {
    int wid  = (blockIdx.x * blockDim.x + threadIdx.x) >> 6;
    if (wid >= nTiles) return;
    int lane = threadIdx.x & 63;
    int m = lane & 15, quad = lane >> 4;
    int rbase = wid * 16;
    const float* zp = z + (size_t)(rbase + m) * IN_CH + quad * 8;
    const short* wp = (const short*)wt + m * IN_CH + quad * 8;
    f32x4 acc[8] = {};
#pragma unroll
    for (int kb = 0; kb < 8; ++kb) {
        float4 f0 = *(const float4*)(zp + kb * 32);
        float4 f1 = *(const float4*)(zp + kb * 32 + 4);
        bf16x8 a;
        a[0] = f2bf(f0.x); a[1] = f2bf(f0.y); a[2] = f2bf(f0.z); a[3] = f2bf(f0.w);
        a[4] = f2bf(f1.x); a[5] = f2bf(f1.y); a[6] = f2bf(f1.z); a[7] = f2bf(f1.w);
#pragma unroll
        for (int n = 0; n < 8; ++n) {
            bf16x8 b = *(const bf16x8*)(wp + n * 16 * IN_CH + kb * 32);
            acc[n] = __builtin_amdgcn_mfma_f32_16x16x32_bf16(a, b, acc[n], 0, 0, 0);
        }
    }
#pragma unroll
    for (int n = 0; n < 8; ++n)
#pragma unroll
        for (int r = 0; r < 4; ++r) {
            int row = rbase + quad * 4 + r;
            x[(size_t)row * NOUT + n * 16 + m] = __float2bfloat16(acc[n][r]);
        }
    // fused attention scores (reduced over the 16 m-lanes of each quad)
    float asv[8], adv[8];
#pragma unroll
    for (int n = 0; n < 8; ++n) {
        asv[n] = att_s[n * 16 + m];
        adv[n] = att_d[n * 16 + m];
    }
    float ps0[4] = {}, ps1[4] = {}, pd0[4] = {}, pd1[4] = {};
#pragma unroll
    for (int r = 0; r < 4; ++r)
#pragma unroll
        for (int n = 0; n < 4; ++n) {
            ps0[r] += acc[n][r] * asv[n];
            ps1[r] += acc[n + 4][r] * asv[n + 4];
            pd0[r] += acc[n][r] * adv[n];
            pd1[r] += acc[n + 4][r] * adv[n + 4];
        }
#pragma unroll
    for (int msk = 1; msk < 16; msk <<= 1)
#pragma unroll
        for (int r = 0; r < 4; ++r) {
            ps0[r] += __shfl_xor(ps0[r], msk);
            ps1[r] += __shfl_xor(ps1[r], msk);
            pd0[r] += __shfl_xor(pd0[r], msk);
            pd1[r] += __shfl_xor(pd1[r], msk);
        }
    if (m < 4) {
        int r = m;
        int row = rbase + quad * 4 + r;
        ((float2*)a_src)[row] = make_float2(ps0[r], ps1[r]);
        ((float2*)a_dst)[row] = make_float2(pd0[r], pd1[r]);
    }
}

// ---------- pass1: pure router. binned[bin*CAPB+slot] = (dstLow<<17)|src ----------
__global__ __launch_bounds__(256) void k_pass1(
        const int* __restrict__ ei,
        int* __restrict__ gcnt, int* __restrict__ binned, int E) {
    __shared__ int lcnt[NBINS];
    __shared__ int lptr[NBINS];
    int t = threadIdx.x;
    int base = blockIdx.x * (256 * EPT);
    lcnt[t] = 0;
    __syncthreads();

    int ent[EPT], bn[EPT];
#pragma unroll
    for (int j = 0; j < EPT; ++j) {
        int e = base + j * 256 + t;
        bn[j] = -1;
        if (e < E) {
            int s = ei[e], d = ei[E + e];
            ent[j] = ((d & (NPB - 1)) << 17) | s;
            bn[j]  = d >> BIN_SHIFT;
            atomicAdd(&lcnt[bn[j]], 1);
        }
    }
    __syncthreads();
    {
        int c = lcnt[t];
        lptr[t] = (c > 0) ? atomicAdd(&gcnt[t], c) : 0;
    }
    __syncthreads();
#pragma unroll
    for (int j = 0; j < EPT; ++j) {
        if (bn[j] >= 0) {
            int pos = atomicAdd(&lptr[bn[j]], 1);
            if (pos < CAPB)
                binned[(size_t)bn[j] * CAPB + pos] = ent[j];
        }
    }
}

// ---------- pass2: per-bin counting sort + exp -> dense epk + per-dst [beg,end] ----------
// bin base from a global cursor (order-independent since beg/end explicit per dst)
__global__ __launch_bounds__(1024) void k_pass2(
        const int* __restrict__ binned, const int* __restrict__ gcnt,
        int* __restrict__ gtot,
        const float* __restrict__ a_src, const float* __restrict__ a_dst,
        int2* __restrict__ epk, int* __restrict__ offsB, int* __restrict__ offsE, int N) {
    __shared__ int    lh[NPB];    // hist, then edge write-ptr
    __shared__ int    lx[NPB];    // inclusive scan
    __shared__ float2 sad[NPB];   // a_dst for this bin
    __shared__ int    sBase;
    int b = blockIdx.x, t = threadIdx.x;
    int nodes = N - b * NPB;
    nodes = (nodes < 0) ? 0 : ((nodes > NPB) ? NPB : nodes);
    if (nodes == 0) return;
    int cnt = gcnt[b];
    if (cnt > CAPB) cnt = CAPB;
    const int* src = binned + (size_t)b * CAPB;

    if (t == 0) sBase = atomicAdd(gtot, cnt + nodes);
    if (t < NPB) {
        lh[t] = (t < nodes) ? 1 : 0;   // self-loop slot
        if (t < nodes) sad[t] = ((const float2*)a_dst)[b * NPB + t];
    }
    __syncthreads();
    for (int i = t; i < cnt; i += 1024)
        atomicAdd(&lh[(src[i] >> 17) & (NPB - 1)], 1);
    __syncthreads();
    if (t < NPB) lx[t] = lh[t];
    __syncthreads();
    for (int off = 1; off < NPB; off <<= 1) {
        int u = (t < NPB && t >= off) ? lx[t - off] : 0;
        __syncthreads();
        if (t < NPB) lx[t] += u;
        __syncthreads();
    }
    int base = sBase;
    int excl = 0;
    if (t < NPB) excl = lx[t] - lh[t];
    __syncthreads();
    if (t < NPB) lh[t] = excl + 1;     // edge write-ptr (slot 0 = self)
    __syncthreads();
    // self-loops + per-dst extents
    if (t < nodes) {
        int d = b * NPB + t;
        float2 as = ((const float2*)a_src)[d];
        float2 ad = sad[t];
        float l0 = as.x + ad.x; l0 = (l0 > 0.f) ? l0 : NEG * l0;
        float l1 = as.y + ad.y; l1 = (l1 > 0.f) ? l1 : NEG * l1;
        epk[base + excl] = make_int2(pack_e(l0, l1), d);
        offsB[d] = base + excl;
        offsE[d] = base + lx[t];
    }
    // placement with exp (scattered 8B within ~150KB window -> L2-merged)
    for (int i = t; i < cnt; i += 1024) {
        int ent = src[i];
        int dLow = (ent >> 17) & (NPB - 1);
        int s = ent & 0x1FFFF;
        float2 as = ((const float2*)a_src)[s];
        float2 ad = sad[dLow];
        float l0 = as.x + ad.x; l0 = (l0 > 0.f) ? l0 : NEG * l0;
        float l1 = as.y + ad.y; l1 = (l1 > 0.f) ? l1 : NEG * l1;
        int pos = atomicAdd(&lh[dLow], 1);
        epk[base + pos] = make_int2(pack_e(l0, l1), s);
    }
}

// ---------- main GAT aggregation: one wave per dst node, single fused pass ----------
// out_h = (sum_i e_i x_i) / (sum_i e_i)
__global__ __launch_bounds__(256) void k_gat_agg(
        const int2* __restrict__ epk,
        const int* __restrict__ offsB, const int* __restrict__ offsE,
        const __hip_bfloat16* __restrict__ x, const float* __restrict__ bias,
        float* __restrict__ out, int N) {
    int wid  = (blockIdx.x * blockDim.x + threadIdx.x) >> 6;
    if (wid >= N) return;
    int lane = threadIdx.x & 63;
    int beg = offsB[wid], end = offsE[wid];
    int h = lane >> 5;   // lanes 0..31: head0 chans, 32..63: head1 chans
    const __hip_bfloat162* xv = (const __hip_bfloat162*)x;

    float ax[4] = {}, ay[4] = {}, dn[4] = {};   // 4 independent chains
    int i = beg;
    for (; i + 3 < end; i += 4) {
#pragma unroll
        for (int u = 0; u < 4; ++u) {
            int2 p = epk[i + u];
            __half2 h2 = *reinterpret_cast<__half2*>(&p.x);
            float2 ef = __half22float2(h2);
            float e = h ? ef.y : ef.x;
            __hip_bfloat162 f = xv[(size_t)p.y * 64 + lane];
            ax[u] += e * __bfloat162float(f.x);
            ay[u] += e * __bfloat162float(f.y);
            dn[u] += e;
        }
    }
    for (; i < end; ++i) {
        int2 p = epk[i];
        __half2 h2 = *reinterpret_cast<__half2*>(&p.x);
        float2 ef = __half22float2(h2);
        float e = h ? ef.y : ef.x;
        __hip_bfloat162 f = xv[(size_t)p.y * 64 + lane];
        ax[0] += e * __bfloat162float(f.x);
        ay[0] += e * __bfloat162float(f.y);
        dn[0] += e;
    }
    float inv = 1.f / ((dn[0] + dn[1]) + (dn[2] + dn[3]));
    float accx = ((ax[0] + ax[1]) + (ax[2] + ax[3])) * inv;
    float accy = ((ay[0] + ay[1]) + (ay[2] + ay[3])) * inv;
    float o0 = accx + __shfl_xor(accx, 32);
    float o1 = accy + __shfl_xor(accy, 32);
    if (lane < 32) {
        int c = 2 * lane;
        float2 o;
        o.x = 0.5f * o0 + bias[c];
        o.y = 0.5f * o1 + bias[c + 1];
        ((float2*)out)[(size_t)wid * 32 + lane] = o;
    }
}

extern "C" void kernel_launch(void* const* d_in, const int* in_sizes, int n_in,
                              void* d_out, int out_size, void* d_ws, size_t ws_size,
                              hipStream_t stream) {
    const float* z     = (const float*)d_in[0];
    const int*   ei    = (const int*)d_in[1];
    const float* W     = (const float*)d_in[2];
    const float* att_s = (const float*)d_in[3];
    const float* att_d = (const float*)d_in[4];
    const float* bias  = (const float*)d_in[5];
    float* out = (float*)d_out;

    const int N = in_sizes[0] / IN_CH;     // 100000
    const int E = in_sizes[1] / 2;         // 3200000
    const int Etot = E + N;

    // workspace carve-up (256B aligned)
    size_t off = 0;
    auto alloc = [&](size_t bytes) {
        void* p = (char*)d_ws + off;
        off += (bytes + 255) & ~(size_t)255;
        return p;
    };
    __hip_bfloat16* x    = (__hip_bfloat16*)alloc((size_t)N * NOUT * 2);
    __hip_bfloat16* Wt   = (__hip_bfloat16*)alloc((size_t)IN_CH * NOUT * 2);
    float* a_src         = (float*)alloc((size_t)N * 2 * 4);
    float* a_dst         = (float*)alloc((size_t)N * 2 * 4);
    int*   gcnt          = (int*)alloc((NBINS + 1) * 4);   // +1: gtot cursor
    int*   gtot          = gcnt + NBINS;
    int*   offsB         = (int*)alloc((size_t)N * 4);
    int*   offsE         = (int*)alloc((size_t)N * 4);
    int*   binned        = (int*)alloc((size_t)NBINS * CAPB * 4);
    int2*  epk           = (int2*)alloc((size_t)Etot * 8);
    (void)ws_size;

    const int nTiles = N / 16;                 // 6250
    const int p1Blocks = (E + 256 * EPT - 1) / (256 * EPT);

    hipMemsetAsync(gcnt, 0, (NBINS + 1) * 4, stream);
    k_transpose_w<<<(IN_CH * NOUT + 255) / 256, 256, 0, stream>>>(W, Wt);
    k_gemm_x<<<(nTiles + 3) / 4, 256, 0, stream>>>(z, Wt, att_s, att_d, x, a_src, a_dst, nTiles);
    k_pass1<<<p1Blocks, 256, 0, stream>>>(ei, gcnt, binned, E);
    k_pass2<<<NBINS, 1024, 0, stream>>>(binned, gcnt, gtot, a_src, a_dst, epk, offsB, offsE, N);
    k_gat_agg<<<(N + 3) / 4, 256, 0, stream>>>(epk, offsB, offsE, x, bias, out, N);
}